// Round 3
// baseline (240.865 us; speedup 1.0000x reference)
//
#include <hip/hip_runtime.h>
#include <hip/hip_fp16.h>

// Problem constants (from reference)
#define N_SAMPLES 524288
#define N_FEATURES 64
#define N_GATES 64
#define N_OUTPUTS 8
#define BASE_COLS 66          // N_FEATURES + 2 (zero col, one col)
#define MAX_CONN 130          // BASE + N_GATES
#define NCOLS 131             // +1 scratch column (130) for dummy-gate writes

// Tiling: 128 threads/block, each thread owns ONE packed fp16x2 LDS word = 2 samples.
#define TPB 256               // samples per block
#define NW 128                // words per row (= threads per block)
#define STR 129               // LDS row stride in words (NW+1)

// d_ws layout (ws_size >= 512 MB, re-poisoned 0xAA each call -> rewrite everything we read)
#define WS_GIDX   0           // int2[64]
#define WS_NCHK   512         // int
#define WS_OWH2   1024        // uint[65*8]  (half2-broadcast weights, row 64 = zeros)
#define WS_ENT    4096        // int4[512]   (chunked gate plan, 8 entries per chunk)

// ---------------------------------------------------------------------------
// Kernel 1: top-2 connection indices per gate, one wave per gate.
// softmax monotone + TEMPERATURE=1 -> top2 of probs == top2 of masked weights.
// Tie-break: lower index wins (matches jax.lax.top_k stable order).
// ---------------------------------------------------------------------------
__device__ inline void top2_ins(float x, int j, float& v1, int& i1, float& v2, int& i2) {
    bool gt1 = (x > v1) || (x == v1 && j < i1);
    bool gt2 = (x > v2) || (x == v2 && j < i2);
    if (gt1) { v2 = v1; i2 = i1; v1 = x; i1 = j; }
    else if (gt2) { v2 = x; i2 = j; }
}

__global__ __launch_bounds__(64) void topk_prep_kernel(const float* __restrict__ gw,
                                                       int2* __restrict__ gidx) {
    const int i = blockIdx.x;        // gate id
    const int l = threadIdx.x;       // lane 0..63
    const float* w = gw + i * MAX_CONN;
    const int avail = BASE_COLS + i;

    float v1 = -1e30f, v2 = -1e30f;
    int   i1 = 0x7fffffff, i2 = 0x7fffffff;
    for (int s = 0; s < 3; ++s) {
        int j = l + 64 * s;
        if (j < avail) top2_ins(w[j], j, v1, i1, v2, i2);
    }
    #pragma unroll
    for (int d = 1; d < 64; d <<= 1) {
        float ov1 = __shfl_xor(v1, d);
        int   oi1 = __shfl_xor(i1, d);
        float ov2 = __shfl_xor(v2, d);
        int   oi2 = __shfl_xor(i2, d);
        top2_ins(ov1, oi1, v1, i1, v2, i2);
        top2_ins(ov2, oi2, v1, i1, v2, i2);
    }
    if (l == 0) gidx[i] = make_int2(i1, i2);
}

// ---------------------------------------------------------------------------
// Kernel 2: build the chunked execution plan + fp16-broadcast weights.
// Greedy: a chunk is a maximal run of gates whose operands all precede the
// run's first gate (always admits >=1 gate since operands of gate i are
// < BASE+i by construction). Runs are emitted in sub-chunks of 8, padded
// with dummy entries {zero-col, zero-col, scratch-col, weight-row 64=zeros}.
// Expected run length ~sqrt(66)~8 for random circuits -> ~10-15 chunks.
// ---------------------------------------------------------------------------
__global__ __launch_bounds__(64) void plan_kernel(const int2* __restrict__ gidx,
                                                  const float* __restrict__ ow,
                                                  char* __restrict__ ws) {
    __shared__ int spa[N_GATES], spb[N_GATES];
    const int t = threadIdx.x;

    unsigned int* owh = (unsigned int*)(ws + WS_OWH2);
    int4* ent = (int4*)(ws + WS_ENT);
    int*  nchk = (int*)(ws + WS_NCHK);

    int2 p = gidx[t];
    spa[t] = p.x; spb[t] = p.y;

    // fp16-broadcast weights: row t from ow, row 64 = zeros
    #pragma unroll
    for (int o = 0; o < N_OUTPUTS; ++o) {
        unsigned short u = __half_as_ushort(__float2half(ow[t * N_OUTPUTS + o]));
        owh[t * N_OUTPUTS + o] = (unsigned int)u * 0x10001u;
    }
    if (t < N_OUTPUTS) owh[N_GATES * N_OUTPUTS + t] = 0u;

    __syncthreads();

    if (t == 0) {
        int i = 0, e = 0;
        while (i < N_GATES) {
            int cs = i;
            int limit = BASE_COLS + cs;                 // cols written before this run
            while (i < N_GATES && spa[i] < limit && spb[i] < limit) ++i;
            for (int j = cs; j < i; ++j)
                ent[e++] = make_int4(spa[j] * STR, spb[j] * STR,
                                     (BASE_COLS + j) * STR, j);
            while (e & 7)
                ent[e++] = make_int4(64 * STR, 64 * STR, 130 * STR, N_GATES);
        }
        *nchk = e >> 3;
    }
}

// ---------------------------------------------------------------------------
// Kernel 3: evaluate circuit. LDS word [c][t] = half2(sample 2t, sample 2t+1).
// Each thread touches ONLY word offset +t -> LDS is a per-thread indexable
// array; no cross-thread deps in the gate loop, conflict-free access.
// ---------------------------------------------------------------------------
__global__ __launch_bounds__(NW) void circuit_kernel(
    const float* __restrict__ X,
    const char*  __restrict__ ws,
    const float* __restrict__ scale,  // [N_OUTPUTS]
    float*       __restrict__ out)    // [N_SAMPLES][N_OUTPUTS]
{
    __shared__ __half2 buf[NCOLS * STR];   // 131*129*4 B = 67,596 B -> 2 blocks/CU

    const int t = threadIdx.x;                      // word owner, 0..127
    const long long s0 = (long long)blockIdx.x * TPB;

    const int4* ent = (const int4*)(ws + WS_ENT);
    const unsigned int* owh = (const unsigned int*)(ws + WS_OWH2);
    const int nc = *(const int*)(ws + WS_NCHK);

    // ---- Stage X chunk (TPB x 64 floats) into LDS, transposed + fp16-packed.
    const float4* Xv = (const float4*)(X + s0 * N_FEATURES);
    #pragma unroll
    for (int k = 0; k < 16; ++k) {
        int q  = k * NW + t;
        int c4 = q & 15;
        int j  = q >> 4;
        float4 va = Xv[(2 * j)     * 16 + c4];
        float4 vb = Xv[(2 * j + 1) * 16 + c4];
        int c = 4 * c4;
        buf[(c + 0) * STR + j] = __halves2half2(__float2half(va.x), __float2half(vb.x));
        buf[(c + 1) * STR + j] = __halves2half2(__float2half(va.y), __float2half(vb.y));
        buf[(c + 2) * STR + j] = __halves2half2(__float2half(va.z), __float2half(vb.z));
        buf[(c + 3) * STR + j] = __halves2half2(__float2half(va.w), __float2half(vb.w));
    }
    buf[64 * STR + t] = __halves2half2(__float2half(0.0f), __float2half(0.0f));
    buf[65 * STR + t] = __halves2half2(__float2half(1.0f), __float2half(1.0f));
    __syncthreads();

    const __half2 one2 = __halves2half2(__float2half(1.0f), __float2half(1.0f));
    __half2 acc[N_OUTPUTS];
    #pragma unroll
    for (int o = 0; o < N_OUTPUTS; ++o) acc[o] = __halves2half2(__float2half(0.0f), __float2half(0.0f));

    // ---- Chunked gate execution: 16 independent ds_reads pipelined per chunk.
    for (int c = 0; c < nc; ++c) {
        int4 E[8];
        #pragma unroll
        for (int j = 0; j < 8; ++j) E[j] = ent[c * 8 + j];

        __half2 av[8], bv[8];
        #pragma unroll
        for (int j = 0; j < 8; ++j) {
            av[j] = buf[E[j].x + t];
            bv[j] = buf[E[j].y + t];
        }
        __half2 gv[8];
        #pragma unroll
        for (int j = 0; j < 8; ++j) {
            gv[j] = __hfma2(__hneg2(av[j]), bv[j], one2);   // 1 - a*b, 2 samples
            buf[E[j].z + t] = gv[j];
        }
        #pragma unroll
        for (int j = 0; j < 8; ++j) {
            const __half2* wrow = (const __half2*)(owh + E[j].w * N_OUTPUTS);
            #pragma unroll
            for (int o = 0; o < N_OUTPUTS; ++o)
                acc[o] = __hfma2(gv[j], wrow[o], acc[o]);
        }
    }

    // ---- Epilogue: scale + coalesced store (4 x float4 per thread).
    float sc[N_OUTPUTS];
    #pragma unroll
    for (int o = 0; o < N_OUTPUTS; ++o) sc[o] = scale[o];

    float a0[N_OUTPUTS], a1[N_OUTPUTS];
    #pragma unroll
    for (int o = 0; o < N_OUTPUTS; ++o) {
        a0[o] = __low2float(acc[o])  * sc[o];
        a1[o] = __high2float(acc[o]) * sc[o];
    }
    float4* outv = (float4*)(out + (s0 + 2 * t) * N_OUTPUTS);
    outv[0] = make_float4(a0[0], a0[1], a0[2], a0[3]);
    outv[1] = make_float4(a0[4], a0[5], a0[6], a0[7]);
    outv[2] = make_float4(a1[0], a1[1], a1[2], a1[3]);
    outv[3] = make_float4(a1[4], a1[5], a1[6], a1[7]);
}

extern "C" void kernel_launch(void* const* d_in, const int* in_sizes, int n_in,
                              void* d_out, int out_size, void* d_ws, size_t ws_size,
                              hipStream_t stream) {
    const float* X     = (const float*)d_in[0];  // [524288][64]
    const float* gw    = (const float*)d_in[1];  // [64][130]
    const float* ow    = (const float*)d_in[2];  // [64][8]
    const float* scale = (const float*)d_in[3];  // [8]
    float* out = (float*)d_out;                  // [524288][8]

    char* ws = (char*)d_ws;
    int2* gidx = (int2*)(ws + WS_GIDX);

    topk_prep_kernel<<<N_GATES, 64, 0, stream>>>(gw, gidx);
    plan_kernel<<<1, 64, 0, stream>>>(gidx, ow, ws);

    int blocks = N_SAMPLES / TPB;                // 2048
    circuit_kernel<<<blocks, NW, 0, stream>>>(X, ws, scale, out);
}